// Round 10
// baseline (24.418 us; speedup 1.0000x reference)
//
#include <hip/hip_runtime.h>
#include <math.h>

// GaussianVisibility: R rays x B=24 bones x G=4 gaussians -> shadow map (R,)
// w2ls (R,24,4,4) fp32 = 100.7 MB stream. Validated model (R8/R9):
// dur = mem_floor(~16.3us @6.3TB/s, already achieved) + VALU_serial (~7.8us).
// Zero overlap regardless of schedule (7 variants). Lever: shrink VALU.
//
// R10 change vs R9 (24.07us): data-driven term culling + trans diet.
//  - Dead-term skip: with S eigenvalues 1/s^2 (s=|N|+1e-3), quad is typically
//    huge -> exp(0.5*resid) ~ 0. __all-uniform skip when resid<-28 or
//    mean<-0.15 (wsig<3e-7): saves ~15 VALU + 4 trans/iter. Error <3e-4.
//  - CDF saturation skip: z=(10-mean)*sqrt(nSn) typically ~+20; at z>5,
//    Phi=1-5e-8 -> skip its exp.
//  - Merged rcp: wsig*cdf = rcp((1+ew)(1+ec)) -> 1 rcp instead of 2.
//  - mean = t*r (t=nSd*r): rn eliminated.
// All branches wave-uniform (__all) -> no divergence; deterministic in the
// fixed inputs. Common path 6->4 trans, dead path 1.
//
// Layout (R4, proven): 8 lanes/ray, oct=(half,sub); lane owns matrix row sub,
// gaussian g=sub, bones 2k+half. o/n rows shared via DPP quad_perm; halves
// merged with __shfl_xor(4). Per-(b,g) params in LDS, once per block.

#define NB 24
#define NG 4
#define BASE_SCALE 0.001f

template <int CTRL>
__device__ __forceinline__ float dpp_f(float x) {
    int r = __builtin_amdgcn_update_dpp(0, __float_as_int(x), CTRL, 0xF, 0xF, true);
    return __int_as_float(r);
}

__device__ __forceinline__ float frcp(float x) { return __builtin_amdgcn_rcpf(x); }

__global__ __launch_bounds__(256, 8) void gauss_vis_kernel(
    const float* __restrict__ w2ls,
    const float* __restrict__ rays_o,
    const float* __restrict__ rays_d,
    const float* __restrict__ Gs,
    float* __restrict__ out,
    int R)
{
    __shared__ float4 P[NB * NG * 3];  // per (b,g): {s00,s01,s02,s11},{s12,s22,mu0,mu1},{mu2,c,-,-}

    const int tid = threadIdx.x;
    const int gid = blockIdx.x * 256 + tid;
    const int ray0 = gid >> 3;
    const int ray = ray0 < R ? ray0 : (R - 1);
    const int oct = tid & 7;   // lane within the ray-octet
    const int sub = oct & 3;   // matrix row + gaussian index
    const int half = oct >> 2; // bone parity

    // ---- per-block param precompute (ray-independent) ----
    if (tid < NB * NG) {
        const float* gp = Gs + tid * 13;
        float mu0 = gp[0], mu1 = gp[1], mu2 = gp[2];
        float s0 = fabsf(gp[3]) + BASE_SCALE;
        float s1 = fabsf(gp[4]) + BASE_SCALE;
        float s2 = fabsf(gp[5]) + BASE_SCALE;
        float ax = gp[6], ay = gp[7], az = gp[8];
        float bx = gp[9], by = gp[10], bz = gp[11];
        float c = fabsf(gp[12]);
        float inv1 = 1.0f / sqrtf(ax * ax + ay * ay + az * az);
        float b1x = ax * inv1, b1y = ay * inv1, b1z = az * inv1;
        float dot = b1x * bx + b1y * by + b1z * bz;
        float t2x = bx - dot * b1x, t2y = by - dot * b1y, t2z = bz - dot * b1z;
        float inv2 = 1.0f / sqrtf(t2x * t2x + t2y * t2y + t2z * t2z);
        float b2x = t2x * inv2, b2y = t2y * inv2, b2z = t2z * inv2;
        float b3x = b1y * b2z - b1z * b2y;
        float b3y = b1z * b2x - b1x * b2z;
        float b3z = b1x * b2y - b1y * b2x;
        float w0 = 1.0f / (s0 * s0), w1 = 1.0f / (s1 * s1), w2 = 1.0f / (s2 * s2);
        float s00 = b1x * b1x * w0 + b1y * b1y * w1 + b1z * b1z * w2;
        float s01 = b1x * b2x * w0 + b1y * b2y * w1 + b1z * b2z * w2;
        float s02 = b1x * b3x * w0 + b1y * b3y * w1 + b1z * b3z * w2;
        float s11 = b2x * b2x * w0 + b2y * b2y * w1 + b2z * b2z * w2;
        float s12 = b2x * b3x * w0 + b2y * b3y * w1 + b2z * b3z * w2;
        float s22 = b3x * b3x * w0 + b3y * b3y * w1 + b3z * b3z * w2;
        P[tid * 3 + 0] = make_float4(s00, s01, s02, s11);
        P[tid * 3 + 1] = make_float4(s12, s22, mu0, mu1);
        P[tid * 3 + 2] = make_float4(mu2, c, 0.f, 0.f);
    }
    __syncthreads();

    const float rox = rays_o[ray * 3 + 0];
    const float roy = rays_o[ray * 3 + 1];
    const float roz = rays_o[ray * 3 + 2];
    const float rdx = rays_d[ray * 3 + 0];
    const float rdy = rays_d[ray * 3 + 1];
    const float rdz = rays_d[ray * 3 + 2];

    // bone b = 2k + half lives at Wp[k*8] (float4 units)
    const float4* __restrict__ Wp =
        (const float4*)w2ls + ((size_t)ray * (NB * 4) + half * 4 + sub);
    const int pi0 = (half * NG + sub) * 3;  // P index for bone `half`, +24 per k

    float sum = 0.f;
#pragma unroll 2
    for (int k = 0; k < 12; ++k) {
        const float4 M = Wp[k * 8];
        float o_s = fmaf(M.x, rox, fmaf(M.y, roy, fmaf(M.z, roz, M.w)));  // homog 1
        float n_s = fmaf(M.x, rdx, fmaf(M.y, rdy, M.z * rdz));            // homog 0
        float o0 = dpp_f<0x00>(o_s), o1 = dpp_f<0x55>(o_s), o2 = dpp_f<0xAA>(o_s);
        float n0 = dpp_f<0x00>(n_s), n1 = dpp_f<0x55>(n_s), n2 = dpp_f<0xAA>(n_s);

        int pi = pi0 + k * 24;
        float4 p0 = P[pi + 0];
        float4 p1 = P[pi + 1];
        float4 p2 = P[pi + 2];
        float s00 = p0.x, s01 = p0.y, s02 = p0.z, s11 = p0.w;
        float s12 = p1.x, s22 = p1.y;
        float d0 = p1.z - o0, d1 = p1.w - o1, d2 = p2.x - o2;  // mu - o
        float c = p2.y;

        float v0 = s00 * n0 + s01 * n1 + s02 * n2;
        float v1 = s01 * n0 + s11 * n1 + s12 * n2;
        float v2 = s02 * n0 + s12 * n1 + s22 * n2;
        float nSn = v0 * n0 + v1 * n1 + v2 * n2;   // n^T S n
        float nSd = v0 * d0 + v1 * d1 + v2 * d2;   // n^T S (mu-o)
        float q0 = s00 * d0 + s01 * d1 + s02 * d2;
        float q1 = s01 * d0 + s11 * d1 + s12 * d2;
        float q2 = s02 * d0 + s12 * d1 + s22 * d2;
        float quad = q0 * d0 + q1 * d1 + q2 * d2;  // d^T S d

        float r = __builtin_amdgcn_rsqf(nSn);      // 1/sqrt(nSn)
        float t = nSd * r;
        float resid = fmaf(t, t, -quad);           // t^2 - quad <= 0; exponent = 0.5*resid
        float mean = t * r;                        // mu_bar

        // dead-term skip (wave-uniform): exp(0.5*resid)<8e-7 or wsig<3e-7
        bool dead = (resid < -28.f) || (mean < -0.15f);
        if (__all(dead)) continue;

        float ew = __expf(1.f - 100.f * mean);     // sigmoid denom part
        float denom = 1.f + ew;

        float z = (10.f - mean) * (nSn * r);       // (10-mean)*sqrt(nSn)
        if (!__all(z > 5.f)) {                     // CDF not saturated somewhere
            float zz = z * z;
            float a = z * fmaf(0.070565992f, zz, 1.5976f);
            denom *= 1.f + __expf(-a);             // cubic-logistic Phi
        }

        float ed = __expf(0.5f * resid);           // density exponent
        sum = fmaf(c * ed, frcp(denom), sum);
    }

    // reduce: quad butterfly (DPP), then merge the two quads of the octet
    sum += dpp_f<0xB1>(sum);       // quad_perm(1,0,3,2)
    sum += dpp_f<0x4E>(sum);       // quad_perm(2,3,0,1)
    sum += __shfl_xor(sum, 4, 64); // half <-> half
    if (oct == 0 && ray0 < R) out[ray0] = __expf(-sum);
}

extern "C" void kernel_launch(void* const* d_in, const int* in_sizes, int n_in,
                              void* d_out, int out_size, void* d_ws, size_t ws_size,
                              hipStream_t stream) {
    const float* w2ls   = (const float*)d_in[0];
    const float* rays_o = (const float*)d_in[1];
    const float* rays_d = (const float*)d_in[2];
    const float* Gs     = (const float*)d_in[3];
    float* out = (float*)d_out;

    const int R = in_sizes[1] / 3;
    const int threads = 256;
    const long long total = (long long)R * 8;
    const int blocks = (int)((total + threads - 1) / threads);
    gauss_vis_kernel<<<blocks, threads, 0, stream>>>(w2ls, rays_o, rays_d, Gs, out, R);
}